// Round 5
// baseline (250.020 us; speedup 1.0000x reference)
//
#include <hip/hip_runtime.h>

// NonLocalBlock: B=8, C=512, N=4096 (64x64), CR=128.
// ws layout (halves):
//   ab  [8][4096][256]  (emb_a 0..127, emb_b 128..255, token-major)   8.39M
//   gC  [8][128][4096]  (channel-major)                                4.19M
//   wi  [384][512] bf16                                                0.20M
//   wo  [512][128] bf16                                                0.07M
//   xbf [8][4096][512]  (token-major bf16 x; yt aliases its head)     16.78M
// yt [8][4096][128] aliases xbf (xbf dead after k_proj, yt written by k_attn).

typedef __attribute__((ext_vector_type(8))) short short8;
typedef __attribute__((ext_vector_type(4))) float f32x4;
typedef __attribute__((ext_vector_type(16))) float f32x16;

__device__ inline unsigned bfr(float f) {   // bf16 round-half-up, result in high half
  union { float f; unsigned u; } v; v.f = f;
  return v.u + 0x8000u;
}
__device__ inline unsigned short f2bf(float f) { return (unsigned short)(bfr(f) >> 16); }
// pack2(a,b) -> [bf16(a) lo, bf16(b) hi] : 2 adds + 1 v_perm_b32
__device__ inline unsigned pack2(float a, float b) {
  return __builtin_amdgcn_perm(bfr(b), bfr(a), 0x07060302u);
}
// XOR-swizzled LDS index (halves). 16B granules: phys = g ^ (row&7).
__device__ inline int sw(int row, int col, int stride_halves) {
  return row * stride_halves + ((((col >> 3) ^ (row & 7)) << 3) | (col & 7));
}
// async global->LDS DMA, 16B per lane; lds dest = wave-uniform base + lane*16
__device__ inline void load_lds16(const void* g, void* l) {
  __builtin_amdgcn_global_load_lds(
      (const __attribute__((address_space(1))) unsigned int*)g,
      (__attribute__((address_space(3))) unsigned int*)l, 16, 0, 0);
}

// ---------------- kernel 0a: weight precompute fp32 -> bf16 ------------------------
__global__ __launch_bounds__(256) void k_prep(const float* __restrict__ w_in,
                                              const float* __restrict__ w_out,
                                              unsigned short* __restrict__ wi,
                                              unsigned short* __restrict__ wo) {
  int i = blockIdx.x * 256 + threadIdx.x;   // 8 floats per thread; 32768 threads
  const float* src;
  unsigned short* dst;
  int base;
  if (i < 24576) { src = w_in;  dst = wi; base = i * 8; }
  else           { src = w_out; dst = wo; base = (i - 24576) * 8; }
  float4 d0 = *(const float4*)&src[base];
  float4 d1 = *(const float4*)&src[base + 4];
  uint4 p;
  p.x = pack2(d0.x, d0.y); p.y = pack2(d0.z, d0.w);
  p.z = pack2(d1.x, d1.y); p.w = pack2(d1.z, d1.w);
  *(uint4*)&dst[base] = p;
}

// ---------------- kernel 0b: x transpose+convert: [b][c][n] f32 -> [b][n][c] bf16 --
// 64c x 64n tile; in-register 4x4 micro-transpose; LDS granule-swizzled by (n>>2)&7.
__global__ __launch_bounds__(256) void k_xpose(const float* __restrict__ x,
                                               unsigned short* __restrict__ xbf) {
  __shared__ unsigned short T[64 * 64];   // [n][c], swizzled
  const int t = threadIdx.x;
  const int n0 = blockIdx.x * 64;
  const int c0 = blockIdx.y * 64;
  const int b = blockIdx.z;

  float4 d[4];
#pragma unroll
  for (int j = 0; j < 4; j++) {
    int c = c0 + (t >> 4) * 4 + j;
    d[j] = *(const float4*)&x[((size_t)(b * 512 + c)) * 4096 + n0 + (t & 15) * 4];
  }
  const float* dp = (const float*)d;
#pragma unroll
  for (int i = 0; i < 4; i++) {
    int n_loc = (t & 15) * 4 + i;
    int c_loc = (t >> 4) * 4;
    uint2 pv;
    pv.x = pack2(dp[0 * 4 + i], dp[1 * 4 + i]);
    pv.y = pack2(dp[2 * 4 + i], dp[3 * 4 + i]);
    int pg = (c_loc >> 3) ^ ((n_loc >> 2) & 7);
    *(uint2*)&T[n_loc * 64 + (pg << 3) + (c_loc & 7)] = pv;
  }
  __syncthreads();
  {
    int n = t >> 2, s = t & 3;
    int x7 = (n >> 2) & 7;
    uint4 lo = *(const uint4*)&T[n * 64 + (((2 * s + 0) ^ x7) << 3)];
    uint4 hi = *(const uint4*)&T[n * 64 + (((2 * s + 1) ^ x7) << 3)];
    unsigned short* dst = &xbf[((size_t)(b * 4096 + n0 + n)) * 512 + c0 + s * 16];
    *(uint4*)&dst[0] = lo;
    *(uint4*)&dst[8] = hi;
  }
}

// ---------------- kernel 1: in-projection GEMM, all-DMA double-buffered ------------
// M=384 (3 o-blocks of 128), K=512 (8 iters of 64), N=4096 (64-token tiles), per b.
// 32x32x16 MFMA; wave w owns o-rows [w*32, w*32+32).
__global__ __launch_bounds__(256) void k_proj(const unsigned short* __restrict__ xbf,
                                              const unsigned short* __restrict__ wi,
                                              unsigned short* __restrict__ ab,
                                              unsigned short* __restrict__ gC) {
  __shared__ unsigned short Abuf[2][128 * 64];   // [o][k] swizzled, 16 KB each
  __shared__ unsigned short Bbuf[2][64 * 64];    // [n][k] swizzled, 8 KB each
  const int t = threadIdx.x;
  const int lane = t & 63;
  const int w = t >> 6;
  const int l31 = lane & 31;
  const int h = lane >> 5;
  const int n0 = blockIdx.x * 64;
  const int o0 = blockIdx.y * 128;
  const int b = blockIdx.z;

  const int arow = w * 32 + (lane >> 3);   // +j*8
  const int brow = w * 16 + (lane >> 3);   // +j*8 (j<2)

  auto dma_tile = [&](int k0, int buf) {
#pragma unroll
    for (int j = 0; j < 4; j++) {          // A: 128 rows x 128 B
      int row = arow + j * 8;
      int gs = (lane & 7) ^ (row & 7);
      load_lds16(&wi[(size_t)(o0 + row) * 512 + k0 + gs * 8],
                 (void*)&Abuf[buf][(w * 32 + j * 8) * 64]);
    }
#pragma unroll
    for (int j = 0; j < 2; j++) {          // B: 64 rows x 128 B
      int row = brow + j * 8;
      int gs = (lane & 7) ^ (row & 7);
      load_lds16(&xbf[((size_t)(b * 4096 + n0 + row)) * 512 + k0 + gs * 8],
                 (void*)&Bbuf[buf][(w * 16 + j * 8) * 64]);
    }
  };

  f32x16 acc[2];
  acc[0] = (f32x16)0.f;
  acc[1] = (f32x16)0.f;

  dma_tile(0, 0);
  __syncthreads();

  for (int it = 0; it < 8; ++it) {
    if (it < 7) dma_tile((it + 1) * 64, (it + 1) & 1);
    const unsigned short* A = Abuf[it & 1];
    const unsigned short* Bm = Bbuf[it & 1];
    short8 af[4];
#pragma unroll
    for (int ks = 0; ks < 4; ks++)
      af[ks] = *(const short8*)&A[sw(w * 32 + l31, ks * 16 + h * 8, 64)];
#pragma unroll
    for (int nt = 0; nt < 2; nt++) {
#pragma unroll
      for (int ks = 0; ks < 4; ks++) {
        short8 bf = *(const short8*)&Bm[sw(nt * 32 + l31, ks * 16 + h * 8, 64)];
        acc[nt] = __builtin_amdgcn_mfma_f32_32x32x16_bf16(af[ks], bf, acc[nt], 0, 0, 0);
      }
    }
    __syncthreads();
  }

  // epilogue: D[o][n]: col=l31 -> n, row=(r&3)+8*(r>>2)+4h -> o
  if (o0 < 256) {
#pragma unroll
    for (int nt = 0; nt < 2; nt++) {
      int n = n0 + nt * 32 + l31;
#pragma unroll
      for (int r = 0; r < 16; r += 2) {
        int o = o0 + w * 32 + (r & 3) + 8 * (r >> 2) + 4 * h;
        *(unsigned*)&ab[((size_t)(b * 4096 + n)) * 256 + o] =
            pack2(acc[nt][r], acc[nt][r + 1]);
      }
    }
  } else {
#pragma unroll
    for (int nt = 0; nt < 2; nt++) {
      int n = n0 + nt * 32 + l31;
#pragma unroll
      for (int r = 0; r < 16; r++) {
        int c = w * 32 + (r & 3) + 8 * (r >> 2) + 4 * h;
        gC[((size_t)(b * 128 + c)) * 4096 + n] = f2bf(acc[nt][r]);
      }
    }
  }
}

// ---------------- kernel 1-fallback: R4 inline k_proj (if ws too small for xbf) ----
__global__ __launch_bounds__(256) void k_proj_inline(const float* __restrict__ x,
                                                     const unsigned short* __restrict__ wi,
                                                     unsigned short* __restrict__ ab,
                                                     unsigned short* __restrict__ gC) {
  __shared__ unsigned short A_lds[128 * 64];
  __shared__ unsigned short B_lds[64 * 64];
  const int t = threadIdx.x;
  const int lane = t & 63;
  const int w = t >> 6;
  const int l15 = lane & 15;
  const int quad = lane >> 4;
  const int n0 = blockIdx.x * 64;
  const int o0 = blockIdx.y * 128;
  const int b = blockIdx.z;
  const int ch8g = t >> 5;
  const int tp = t & 31;

  f32x4 acc[2][4];
#pragma unroll
  for (int i = 0; i < 2; i++)
#pragma unroll
    for (int j = 0; j < 4; j++) acc[i][j] = (f32x4)0.f;

  for (int k0 = 0; k0 < 512; k0 += 64) {
#pragma unroll
    for (int j = 0; j < 4; j++) {
      int row = w * 32 + j * 8 + (lane >> 3);
      int gs = (lane & 7) ^ (row & 7);
      load_lds16(&wi[(size_t)(o0 + row) * 512 + k0 + gs * 8],
                 (void*)&A_lds[(w * 32 + j * 8) * 64]);
    }
    {
      float2 d[8];
#pragma unroll
      for (int j = 0; j < 8; j++)
        d[j] = *(const float2*)&x[((size_t)(b * 512 + k0 + ch8g * 8 + j)) * 4096 + n0 + tp * 2];
#pragma unroll
      for (int i = 0; i < 2; i++) {
        int r = tp * 2 + i;
        uint4 pv;
        if (i == 0) {
          pv.x = pack2(d[0].x, d[1].x); pv.y = pack2(d[2].x, d[3].x);
          pv.z = pack2(d[4].x, d[5].x); pv.w = pack2(d[6].x, d[7].x);
        } else {
          pv.x = pack2(d[0].y, d[1].y); pv.y = pack2(d[2].y, d[3].y);
          pv.z = pack2(d[4].y, d[5].y); pv.w = pack2(d[6].y, d[7].y);
        }
        *(uint4*)&B_lds[sw(r, ch8g * 8, 64)] = pv;
      }
    }
    __syncthreads();
#pragma unroll
    for (int kk = 0; kk < 64; kk += 32) {
      short8 a0 = *(const short8*)&A_lds[sw(w * 32 + l15, kk + quad * 8, 64)];
      short8 a1 = *(const short8*)&A_lds[sw(w * 32 + 16 + l15, kk + quad * 8, 64)];
#pragma unroll
      for (int ns = 0; ns < 4; ns++) {
        short8 bb = *(const short8*)&B_lds[sw(ns * 16 + l15, kk + quad * 8, 64)];
        acc[0][ns] = __builtin_amdgcn_mfma_f32_16x16x32_bf16(a0, bb, acc[0][ns], 0, 0, 0);
        acc[1][ns] = __builtin_amdgcn_mfma_f32_16x16x32_bf16(a1, bb, acc[1][ns], 0, 0, 0);
      }
    }
    __syncthreads();
  }
  if (o0 < 256) {
#pragma unroll
    for (int ms = 0; ms < 2; ms++) {
      int o = o0 + w * 32 + ms * 16 + quad * 4;
#pragma unroll
      for (int ns = 0; ns < 4; ns++) {
        int n = n0 + ns * 16 + l15;
        uint2 p;
        p.x = pack2(acc[ms][ns][0], acc[ms][ns][1]);
        p.y = pack2(acc[ms][ns][2], acc[ms][ns][3]);
        *(uint2*)&ab[((size_t)(b * 4096 + n)) * 256 + o] = p;
      }
    }
  } else {
#pragma unroll
    for (int ms = 0; ms < 2; ms++) {
      int og = w * 32 + ms * 16 + quad * 4;
#pragma unroll
      for (int ns = 0; ns < 4; ns++) {
        int n = n0 + ns * 16 + l15;
#pragma unroll
        for (int r = 0; r < 4; r++)
          gC[((size_t)(b * 128 + og + r)) * 4096 + n] = f2bf(acc[ms][ns][r]);
      }
    }
  }
}

// ---------------- kernel 2: flash attention, 32x32x16 MFMA, DMA double-buffer -------
__global__ __launch_bounds__(256, 2) void k_attn(const unsigned short* __restrict__ ab,
                                                 const unsigned short* __restrict__ gC,
                                                 unsigned short* __restrict__ yt) {
  __shared__ uint4 smem4[65536 / 16];                       // 64 KB
  unsigned short* smem_h = (unsigned short*)smem4;
  float* Obuf = (float*)smem4;                              // epilogue [64 q][129 c]
  float* lsumbuf = (float*)((char*)smem4 + 33024);          // [64]
  unsigned* Pbuf = (unsigned*)((char*)smem4 + 33280);       // [64 q][65]

  const int t = threadIdx.x;
  const int lane = t & 63;
  const int w = t >> 6;
  const int wr = w & 1;
  const int wc = w >> 1;
  const int l31 = lane & 31;
  const int h = lane >> 5;
  const int l7 = l31 & 7;
  const int q0 = blockIdx.x * 64;
  const int b = blockIdx.y;

  short8 qf[8];
  {
    const unsigned short* qp = &ab[((size_t)(b * 4096 + q0 + wc * 32 + l31)) * 256 + h * 8];
#pragma unroll
    for (int ks = 0; ks < 8; ks++) qf[ks] = *(const short8*)&qp[ks * 16];
  }

  const int krow_c = w * 16 + (lane >> 4);
  const int vrow_c = w * 32 + (lane >> 3);

  auto dma_tile = [&](int kt, int buf) {
    unsigned short* Kb = smem_h + buf * 8192;
    unsigned short* Vb = smem_h + 16384 + buf * 8192;
#pragma unroll
    for (int j = 0; j < 4; j++) {
      int row = krow_c + j * 4;
      int gs = (lane & 15) ^ (row & 7);
      load_lds16(&ab[((size_t)(b * 4096 + kt + row)) * 256 + 128 + gs * 8],
                 (void*)&Kb[(w * 16 + j * 4) * 128]);
    }
#pragma unroll
    for (int j = 0; j < 4; j++) {
      int row = vrow_c + j * 8;
      int gs = (lane & 7) ^ (row & 7);
      load_lds16(&gC[((size_t)(b * 128 + row)) * 4096 + kt + gs * 8],
                 (void*)&Vb[(w * 32 + j * 8) * 64]);
    }
  };

  f32x16 O[4];
#pragma unroll
  for (int i = 0; i < 4; i++) O[i] = (f32x16)0.f;
  float lsum = 0.f;
  const int rowK = wr * 32 + l31;

  dma_tile(0, 0);
  __syncthreads();

  for (int it = 0; it < 64; ++it) {
    if (it < 63) dma_tile((it + 1) * 64, (it + 1) & 1);
    const unsigned short* Kc = smem_h + (it & 1) * 8192;
    const unsigned short* Vc = smem_h + 16384 + (it & 1) * 8192;

    f32x16 accS = (f32x16)0.f;
#pragma unroll
    for (int ks = 0; ks < 8; ks++) {
      short8 ak = *(const short8*)&Kc[rowK * 128 + (((ks * 2 + h) ^ l7) << 3)];
      accS = __builtin_amdgcn_mfma_f32_32x32x16_bf16(ak, qf[ks], accS, 0, 0, 0);
    }

    float ps[16];
#pragma unroll
    for (int r = 0; r < 16; r++) {
      ps[r] = __expf(accS[r]);
      lsum += ps[r];
    }
    unsigned u[8];
#pragma unroll
    for (int i = 0; i < 8; i++) u[i] = pack2(ps[2 * i], ps[2 * i + 1]);

    short8 pfrag[2];
#pragma unroll
    for (int f = 0; f < 2; f++) {
      unsigned a0 = u[4 * f + 0], a1 = u[4 * f + 1], a2 = u[4 * f + 2], a3 = u[4 * f + 3];
      unsigned r0 = __shfl_xor(h ? a0 : a2, 32);
      unsigned r1 = __shfl_xor(h ? a1 : a3, 32);
      union { unsigned uu[4]; short8 s; } cv;
      if (h == 0) { cv.uu[0] = a0; cv.uu[1] = a1; cv.uu[2] = r0; cv.uu[3] = r1; }
      else        { cv.uu[0] = r0; cv.uu[1] = r1; cv.uu[2] = a2; cv.uu[3] = a3; }
      pfrag[f] = cv.s;
    }

#pragma unroll
    for (int ct = 0; ct < 4; ct++) {
      int rowV = ct * 32 + l31;
#pragma unroll
      for (int f = 0; f < 2; f++) {
        short8 av = *(const short8*)&Vc[rowV * 64 + (((wr * 4 + f * 2 + h) ^ l7) << 3)];
        O[ct] = __builtin_amdgcn_mfma_f32_32x32x16_bf16(av, pfrag[f], O[ct], 0, 0, 0);
      }
    }
    __syncthreads();
  }

  lsum += __shfl_xor(lsum, 32);
  const int q = wc * 32 + l31;
  if (wr == 0) {
#pragma unroll
    for (int ct = 0; ct < 4; ct++)
#pragma unroll
      for (int r = 0; r < 16; r++) {
        int c = ct * 32 + (r & 3) + 8 * (r >> 2) + 4 * h;
        Obuf[q * 129 + c] = O[ct][r];
      }
    if (h == 0) lsumbuf[q] = lsum;
  }
  __syncthreads();
  if (wr == 1) {
    float linv = 1.f / (lsum + lsumbuf[q]);
#pragma unroll
    for (int ct = 0; ct < 4; ct++)
#pragma unroll
      for (int r = 0; r < 16; r += 2) {
        int c = ct * 32 + (r & 3) + 8 * (r >> 2) + 4 * h;
        float v0 = (Obuf[q * 129 + c] + O[ct][r]) * linv;
        float v1 = (Obuf[q * 129 + c + 1] + O[ct][r + 1]) * linv;
        Pbuf[q * 65 + (c >> 1)] = pack2(v0, v1);
      }
  }
  __syncthreads();
  {
    int qq = t >> 2, seg = t & 3;
    unsigned* yrow = (unsigned*)&yt[((size_t)(b * 4096 + q0 + qq)) * 128];
#pragma unroll
    for (int i = 0; i < 4; i++) {
      uint4 v;
      v.x = Pbuf[qq * 65 + seg * 16 + i * 4 + 0];
      v.y = Pbuf[qq * 65 + seg * 16 + i * 4 + 1];
      v.z = Pbuf[qq * 65 + seg * 16 + i * 4 + 2];
      v.w = Pbuf[qq * 65 + seg * 16 + i * 4 + 3];
      *(uint4*)&yrow[seg * 16 + i * 4] = v;
    }
  }
}

// ---------------- kernel 3: out-projection GEMM (M=512, K=128, N=4096) + residual ---
__global__ __launch_bounds__(256) void k_out(const float* __restrict__ x,
                                             const unsigned short* __restrict__ wo,
                                             const unsigned short* __restrict__ yt,
                                             float* __restrict__ out) {
  __shared__ unsigned short A_lds[128 * 128];
  __shared__ unsigned short B_lds[64 * 128];
  const int t = threadIdx.x;
  const int lane = t & 63;
  const int w = t >> 6;
  const int l15 = lane & 15;
  const int quad = lane >> 4;
  const int n0 = blockIdx.x * 64;
  const int o0 = blockIdx.y * 128;
  const int b = blockIdx.z;

#pragma unroll
  for (int j = 0; j < 8; j++) {
    int row = w * 32 + j * 4 + (lane >> 4);
    int gs = (lane & 15) ^ (row & 7);
    load_lds16(&wo[(size_t)(o0 + row) * 128 + gs * 8],
               (void*)&A_lds[(w * 32 + j * 4) * 128]);
  }
#pragma unroll
  for (int j = 0; j < 4; j++) {
    int row = w * 16 + j * 4 + (lane >> 4);
    int gs = (lane & 15) ^ (row & 7);
    load_lds16(&yt[((size_t)(b * 4096 + n0 + row)) * 128 + gs * 8],
               (void*)&B_lds[(w * 16 + j * 4) * 128]);
  }
  __syncthreads();

  f32x4 acc[2][4];
#pragma unroll
  for (int i = 0; i < 2; i++)
#pragma unroll
    for (int j = 0; j < 4; j++) acc[i][j] = (f32x4)0.f;
#pragma unroll
  for (int ks = 0; ks < 4; ks++) {
    short8 a0 = *(const short8*)&A_lds[sw(w * 32 + l15, ks * 32 + quad * 8, 128)];
    short8 a1 = *(const short8*)&A_lds[sw(w * 32 + 16 + l15, ks * 32 + quad * 8, 128)];
#pragma unroll
    for (int ns = 0; ns < 4; ns++) {
      short8 bb = *(const short8*)&B_lds[sw(ns * 16 + l15, ks * 32 + quad * 8, 128)];
      acc[0][ns] = __builtin_amdgcn_mfma_f32_16x16x32_bf16(a0, bb, acc[0][ns], 0, 0, 0);
      acc[1][ns] = __builtin_amdgcn_mfma_f32_16x16x32_bf16(a1, bb, acc[1][ns], 0, 0, 0);
    }
  }
#pragma unroll
  for (int ms = 0; ms < 2; ms++) {
    int o = o0 + w * 32 + ms * 16 + quad * 4;
#pragma unroll
    for (int ns = 0; ns < 4; ns++) {
      int n = n0 + ns * 16 + l15;
#pragma unroll
      for (int r = 0; r < 4; r++) {
        size_t off = ((size_t)(b * 512 + o + r)) * 4096 + n;
        out[off] = x[off] + acc[ms][ns][r];
      }
    }
  }
}

extern "C" void kernel_launch(void* const* d_in, const int* in_sizes, int n_in,
                              void* d_out, int out_size, void* d_ws, size_t ws_size,
                              hipStream_t stream) {
  const float* x = (const float*)d_in[0];
  const float* w_in = (const float*)d_in[1];
  const float* w_out = (const float*)d_in[2];
  float* out = (float*)d_out;

  unsigned short* ab = (unsigned short*)d_ws;                 // 8,388,608 halves
  unsigned short* gC = ab + (size_t)8 * 4096 * 256;           // 4,194,304
  unsigned short* wi = gC + (size_t)8 * 128 * 4096;           // 196,608
  unsigned short* wo = wi + (size_t)384 * 512;                // 65,536
  unsigned short* xbf = wo + (size_t)512 * 128;               // 16,777,216
  const size_t need_big = (size_t)(8388608 + 4194304 + 196608 + 65536 + 16777216) * 2;

  k_prep<<<128, 256, 0, stream>>>(w_in, w_out, wi, wo);
  if (ws_size >= need_big) {
    unsigned short* yt = xbf;   // aliases xbf head; xbf dead after k_proj
    k_xpose<<<dim3(64, 8, 8), 256, 0, stream>>>(x, xbf);
    k_proj<<<dim3(64, 3, 8), 256, 0, stream>>>(xbf, wi, ab, gC);
    k_attn<<<dim3(64, 8), 256, 0, stream>>>(ab, gC, yt);
    k_out<<<dim3(64, 4, 8), 256, 0, stream>>>(x, wo, yt, out);
  } else {
    unsigned short* yt = xbf;   // fits in the small footprint too (4.19M halves)
    k_proj_inline<<<dim3(64, 3, 8), 256, 0, stream>>>(x, wi, ab, gC);
    k_attn<<<dim3(64, 8), 256, 0, stream>>>(ab, gC, yt);
    k_out<<<dim3(64, 4, 8), 256, 0, stream>>>(x, wo, yt, out);
  }
}